// Round 5
// baseline (79.357 us; speedup 1.0000x reference)
//
#include <hip/hip_runtime.h>
#include <stdint.h>

// DSVDD fused: dist = sqrt(||phi||^2 + ||c||^2 - 2 phi.c), top-3 smallest, softmin score.
// bf16 MFMA computes S = phi.c - ||c||^2/2 (centers folded into K-pad 112->128),
// track top-3 LARGEST S per row == 3 smallest distances.
// R5: same structure as R4, but stage1 occupancy PINNED to exactly 4 waves/EU
// (amdgpu_waves_per_eu(4,4)) -> 128-reg budget. R4's launch_bounds(256,4) let the
// compiler squeeze to 64 VGPR (8 waves/EU) and spill ~50 regs -> WRITE_SIZE 65 MB.

typedef short s16x8 __attribute__((ext_vector_type(8)));
typedef float fx4 __attribute__((ext_vector_type(4)));

#define M_TOT 3136
#define CC 112
#define NROWS 50176
#define N_TILES_TOT 50  // 3200 m / 64 per tile

__device__ __forceinline__ unsigned short f2bf(float x) {
  unsigned u = __float_as_uint(x);
  u += 0x7fffu + ((u >> 16) & 1u);  // RNE
  return (unsigned short)(u >> 16);
}

__device__ __forceinline__ void async16(const void* g, void* l) {
  __builtin_amdgcn_global_load_lds(
      (const __attribute__((address_space(1))) unsigned int*)g,
      (__attribute__((address_space(3))) unsigned int*)l, 16, 0, 0);
}

// insert v into descending triple (t0 >= t1 >= t2), keep 3 largest. 3 VALU ops.
#define INSERT3(T0, T1, T2, V)                                  \
  do {                                                          \
    const float _a0 = (T0), _a1 = (T1), _v = (V);               \
    (T0) = fmaxf(_a0, _v);                                      \
    (T1) = __builtin_amdgcn_fmed3f(_a0, _a1, _v);               \
    (T2) = __builtin_amdgcn_fmed3f(_a1, (T2), _v);              \
  } while (0)

// ---- prep: C_bank (112 x 3136 f32) -> CT (3200 x 128 bf16), centers folded ----
// CT[m][k]: k=0..111 = C_bank[k][m]; k=112..115 = -||c_m||^2/8 (sentinel -2500); rest 0.
// 16B-block b of row m stored at byte (b ^ (m&15))*16  (bank swizzle for ds_read_b128).
__global__ __launch_bounds__(256) void dsvdd_prep(const float* __restrict__ Cb,
                                                  unsigned char* __restrict__ CTg) {
  const int i = threadIdx.x & 63;
  const int q = threadIdx.x >> 6;
  const int m = blockIdx.x * 64 + i;
  const bool valid = (m < M_TOT);
  __shared__ float part[4][64];
  float ss = 0.f;
  const int b0 = q * 4;
  const int nb = (q == 3) ? 2 : 4;  // blocks 14,15 are special
  for (int jb = 0; jb < nb; ++jb) {
    const int b = b0 + jb;
    float v[8];
#pragma unroll
    for (int j = 0; j < 8; ++j) {
      v[j] = valid ? Cb[(size_t)(b * 8 + j) * M_TOT + m] : 0.f;
      ss += v[j] * v[j];
    }
    uint4 pk;
    pk.x = (unsigned)f2bf(v[0]) | ((unsigned)f2bf(v[1]) << 16);
    pk.y = (unsigned)f2bf(v[2]) | ((unsigned)f2bf(v[3]) << 16);
    pk.z = (unsigned)f2bf(v[4]) | ((unsigned)f2bf(v[5]) << 16);
    pk.w = (unsigned)f2bf(v[6]) | ((unsigned)f2bf(v[7]) << 16);
    *(uint4*)(CTg + (size_t)m * 256 + ((b ^ (m & 15)) * 16)) = pk;
  }
  part[q][i] = ss;
  __syncthreads();
  if (q == 0) {
    const float c2 = part[0][i] + part[1][i] + part[2][i] + part[3][i];
    const float slot = valid ? (-0.125f * c2) : -2500.0f;  // sentinel: S = -1e4
    const unsigned sb = f2bf(slot);
    const unsigned ww = sb | (sb << 16);
    uint4 blk;
    blk.x = ww; blk.y = ww; blk.z = 0u; blk.w = 0u;
    *(uint4*)(CTg + (size_t)m * 256 + ((14 ^ (m & 15)) * 16)) = blk;
    uint4 zz;
    zz.x = zz.y = zz.z = zz.w = 0u;
    *(uint4*)(CTg + (size_t)m * 256 + ((15 ^ (m & 15)) * 16)) = zz;
  }
}

// ---- stage1: block = 128 rows x (nT tiles of 64 m); 4 waves = 2 row-groups x 2 m-halves
__global__ __attribute__((amdgpu_flat_work_group_size(256, 256)))
__attribute__((amdgpu_waves_per_eu(4, 4)))
void dsvdd_stage1(const float* __restrict__ phi,
                  const unsigned char* __restrict__ CTg,
                  float* __restrict__ part,
                  float* __restrict__ featg, int nT) {
  __shared__ __align__(16) unsigned char lds[32768];
  unsigned char* const buf0 = lds;
  unsigned char* const buf1 = lds + 16384;

  const int t = threadIdx.x;
  const int lane = t & 63;
  const int w = t >> 6;
  const int g = w >> 1;  // row-group: rows [g*64, g*64+64)
  const int h = w & 1;   // m-half of each 64-m tile: [h*32, h*32+32)
  const int cq = lane & 15;
  const int kq = lane >> 4;
  const int c = blockIdx.y;
  const int tile0 = c * nT;
  const long rowBase = (long)blockIdx.x * 128;

  // issue CT tile0 stage early (overlaps the phi prologue)
  {
    const unsigned char* gsrc = CTg + (size_t)tile0 * 16384 + w * 1024 + lane * 16;
    unsigned char* ldst = buf0 + w * 1024;
#pragma unroll
    for (int r = 0; r < 4; ++r) async16(gsrc + r * 4096, ldst + r * 4096);
  }

  // ---- phi -> bg fragments directly (64 rows/wave, 64 VGPR) + row features ----
  s16x8 bg[4][4];  // [ks][pf]
  float ssr[4];
#pragma unroll
  for (int pf = 0; pf < 4; ++pf) {
    ssr[pf] = 0.f;
    const float* rp = phi + (size_t)(rowBase + g * 64 + pf * 16 + cq) * CC;
#pragma unroll
    for (int ks = 0; ks < 4; ++ks) {
      const int k0 = ks * 32 + kq * 8;
      s16x8 v;
      if (k0 <= 104) {  // 8 in-bounds f32
        const float4 a = *(const float4*)(rp + k0);
        const float4 b = *(const float4*)(rp + k0 + 4);
        ssr[pf] += a.x * a.x + a.y * a.y + a.z * a.z + a.w * a.w;
        ssr[pf] += b.x * b.x + b.y * b.y + b.z * b.z + b.w * b.w;
        v[0] = (short)f2bf(a.x); v[1] = (short)f2bf(a.y);
        v[2] = (short)f2bf(a.z); v[3] = (short)f2bf(a.w);
        v[4] = (short)f2bf(b.x); v[5] = (short)f2bf(b.y);
        v[6] = (short)f2bf(b.z); v[7] = (short)f2bf(b.w);
      } else if (k0 == 112) {  // fold slots: four 1.0, four 0
        v[0] = v[1] = v[2] = v[3] = (short)0x3f80;
        v[4] = v[5] = v[6] = v[7] = 0;
      } else {
        v = (s16x8)0;
      }
      bg[ks][pf] = v;
    }
    ssr[pf] += __shfl_xor(ssr[pf], 16);
    ssr[pf] += __shfl_xor(ssr[pf], 32);
  }
  if (c == 0 && kq == 0) {
#pragma unroll
    for (int pf = 0; pf < 4; ++pf)
      featg[rowBase + g * 64 + pf * 16 + cq] = ssr[pf];
  }

  float t0[4], t1[4], t2[4];
#pragma unroll
  for (int pf = 0; pf < 4; ++pf) t0[pf] = t1[pf] = t2[pf] = -3.0e38f;

  __syncthreads();  // tile0 landed (barrier drains vmcnt)

  for (int tt = 0; tt < nT; ++tt) {
    const unsigned char* rd = (tt & 1) ? buf1 : buf0;
    unsigned char* wr = (tt & 1) ? buf0 : buf1;
    if (tt + 1 < nT) {  // stage next tile into the buffer freed at the previous barrier
      const unsigned char* gsrc =
          CTg + (size_t)(tile0 + tt + 1) * 16384 + w * 1024 + lane * 16;
      unsigned char* ldst = wr + w * 1024;
#pragma unroll
      for (int r = 0; r < 4; ++r) async16(gsrc + r * 4096, ldst + r * 4096);
    }
#pragma unroll
    for (int mf = 0; mf < 2; ++mf) {
      const unsigned char* abase = rd + (h * 32 + mf * 16 + cq) * 256;
      s16x8 af[4];
#pragma unroll
      for (int ks = 0; ks < 4; ++ks)
        af[ks] = *(const s16x8*)(abase + (((ks * 4 + kq) ^ cq) * 16));
      fx4 acc[4];
      const fx4 zz = {0.f, 0.f, 0.f, 0.f};
#pragma unroll
      for (int ks = 0; ks < 4; ++ks)
#pragma unroll
        for (int pf = 0; pf < 4; ++pf)
          acc[pf] = __builtin_amdgcn_mfma_f32_16x16x32_bf16(
              af[ks], bg[ks][pf], (ks == 0) ? zz : acc[pf], 0, 0, 0);
#pragma unroll
      for (int pf = 0; pf < 4; ++pf)
#pragma unroll
        for (int rg = 0; rg < 4; ++rg)
          INSERT3(t0[pf], t1[pf], t2[pf], acc[pf][rg]);
    }
    __syncthreads();  // next tile landed + everyone done reading rd
  }

  // ---- merge the 4 kq groups within each wave ----
#pragma unroll
  for (int pf = 0; pf < 4; ++pf) {
#pragma unroll
    for (int off = 16; off < 64; off <<= 1) {
      const float b0 = __shfl_xor(t0[pf], off);
      const float b1 = __shfl_xor(t1[pf], off);
      const float b2 = __shfl_xor(t2[pf], off);
      INSERT3(t0[pf], t1[pf], t2[pf], b0);
      INSERT3(t0[pf], t1[pf], t2[pf], b1);
      INSERT3(t0[pf], t1[pf], t2[pf], b2);
    }
  }
  // merge the 2 m-halves via LDS (alias buf0; all CT reads finished at last barrier)
  float(*const mg)[8] = (float(*)[8])lds;  // [128 rows][h*3+..]
  if (kq == 0) {
#pragma unroll
    for (int pf = 0; pf < 4; ++pf) {
      const int row = g * 64 + pf * 16 + cq;
      mg[row][h * 3 + 0] = t0[pf];
      mg[row][h * 3 + 1] = t1[pf];
      mg[row][h * 3 + 2] = t2[pf];
    }
  }
  __syncthreads();
  if (t < 128) {
    float s0 = mg[t][0], s1 = mg[t][1], s2 = mg[t][2];
    INSERT3(s0, s1, s2, mg[t][3]);
    INSERT3(s0, s1, s2, mg[t][4]);
    INSERT3(s0, s1, s2, mg[t][5]);
    float* dst = part + ((size_t)c * NROWS + rowBase + t) * 3;
    dst[0] = s0; dst[1] = s1; dst[2] = s2;
  }
}

// ---- stage2: merge S partial triples per row, sqrt + softmin, write score ----
__global__ __launch_bounds__(256) void dsvdd_stage2(const float* __restrict__ part,
                                                    const float* __restrict__ featg,
                                                    float* __restrict__ out, int S) {
  const int row = blockIdx.x * 256 + threadIdx.x;
  if (row >= NROWS) return;
  float s0 = -3.0e38f, s1 = -3.0e38f, s2 = -3.0e38f;
  for (int c = 0; c < S; ++c) {
    const float* p = part + ((size_t)c * NROWS + row) * 3;
    INSERT3(s0, s1, s2, p[0]);
    INSERT3(s0, s1, s2, p[1]);
    INSERT3(s0, s1, s2, p[2]);
  }
  const float feat = featg[row];
  const float d0 = sqrtf(fmaxf(feat - 2.f * s0, 0.f));
  const float d1 = sqrtf(fmaxf(feat - 2.f * s1, 0.f));
  const float d2 = sqrtf(fmaxf(feat - 2.f * s2, 0.f));
  const float w0 = 1.0f / (1.0f + __expf(d0 - d1) + __expf(d0 - d2));
  out[row] = w0 * d0;
}

extern "C" void kernel_launch(void* const* d_in, const int* in_sizes, int n_in,
                              void* d_out, int out_size, void* d_ws, size_t ws_size,
                              hipStream_t stream) {
  (void)in_sizes; (void)n_in; (void)out_size;
  const float* phi = (const float*)d_in[0];
  const float* Cb = (const float*)d_in[1];
  float* out = (float*)d_out;
  unsigned char* CTg = (unsigned char*)d_ws;              // 819200 B
  float* featg = (float*)((unsigned char*)d_ws + 819200); // 200704 B
  float* partp = (float*)((unsigned char*)d_ws + 819200 + 200704);
  const size_t base = 819200 + 200704;
  int S = 1;
  if (ws_size >= base + (size_t)5 * NROWS * 12) S = 5;
  else if (ws_size >= base + (size_t)2 * NROWS * 12) S = 2;
  const int nT = N_TILES_TOT / S;
  dsvdd_prep<<<50, 256, 0, stream>>>(Cb, CTg);
  dsvdd_stage1<<<dim3(392, S), 256, 0, stream>>>(phi, CTg, partp, featg, nT);
  dsvdd_stage2<<<196, 256, 0, stream>>>(partp, featg, out, S);
}

// Round 6
// 76.652 us; speedup vs baseline: 1.0353x; 1.0353x over previous
//
#include <hip/hip_runtime.h>
#include <stdint.h>

// DSVDD fused: dist = sqrt(||phi||^2 + ||c||^2 - 2 phi.c), top-3 smallest, softmin score.
// bf16 MFMA computes S = phi.c - ||c||^2/2 (centers folded into K-pad 112->128),
// track top-3 LARGEST S per row == 3 smallest distances.
// R6: (a) launch_bounds(256,2) -> 256-reg cap, kills the 33-dword/thread spill seen at
// VGPR_Count=64 (WRITE_SIZE 65.8MB); (b) CT2 stored in FRAGMENT ORDER [tile][f][ks][lane]
// so global_load_lds dest is linear and ds_read_b128 is contiguous/conflict-free;
// (c) triple-buffered LDS (48KB) with counted s_waitcnt vmcnt(4) + raw s_barrier:
// one barrier/tile, vmcnt never drained to 0 in-loop, 2 tiles always in flight.

typedef short s16x8 __attribute__((ext_vector_type(8)));
typedef float fx4 __attribute__((ext_vector_type(4)));

#define M_TOT 3136
#define CC 112
#define NROWS 50176
#define N_TILES_TOT 50  // 3200 m / 64 per tile; tile bytes = 64*256 = 16384

__device__ __forceinline__ unsigned short f2bf(float x) {
  unsigned u = __float_as_uint(x);
  u += 0x7fffu + ((u >> 16) & 1u);  // RNE
  return (unsigned short)(u >> 16);
}

__device__ __forceinline__ void async16(const void* g, void* l) {
  __builtin_amdgcn_global_load_lds(
      (const __attribute__((address_space(1))) unsigned int*)g,
      (__attribute__((address_space(3))) unsigned int*)l, 16, 0, 0);
}

// insert v into descending triple (t0 >= t1 >= t2), keep 3 largest. 3 VALU ops.
#define INSERT3(T0, T1, T2, V)                                  \
  do {                                                          \
    const float _a0 = (T0), _a1 = (T1), _v = (V);               \
    (T0) = fmaxf(_a0, _v);                                      \
    (T1) = __builtin_amdgcn_fmed3f(_a0, _a1, _v);               \
    (T2) = __builtin_amdgcn_fmed3f(_a1, (T2), _v);              \
  } while (0)

// ---- prep0: c2g[m] = ||c_m||^2 for m<M_TOT else 20000 (sentinel -> fold slot -2500) ----
__global__ __launch_bounds__(256) void dsvdd_prep0(const float* __restrict__ Cb,
                                                   float* __restrict__ c2g) {
  const int m = blockIdx.x * 256 + threadIdx.x;
  if (m >= 3200) return;
  float ss = 20000.0f;
  if (m < M_TOT) {
    ss = 0.f;
    for (int k = 0; k < CC; ++k) {
      const float x = Cb[(size_t)k * M_TOT + m];
      ss += x * x;
    }
  }
  c2g[m] = ss;
}

// ---- prep1: CT2[tile][f][ks][lane] 16B slots, fragment-ordered for MFMA A-operand ----
// slot value: 8 bf16 = CT[m = tile*64+f*16+(lane&15)][k = ks*32+(lane>>4)*8 + 0..7]
// where CT[m][k] = C_bank[k][m] (k<112); -c2[m]/8 (112<=k<116); 0 (k>=116).
__global__ __launch_bounds__(256) void dsvdd_prep1(const float* __restrict__ Cb,
                                                   const float* __restrict__ c2g,
                                                   unsigned char* __restrict__ CT2) {
  const int tile = blockIdx.x;
#pragma unroll
  for (int it = 0; it < 4; ++it) {
    const int s = it * 256 + threadIdx.x;  // 0..1023 slots per tile
    const int f = s >> 8;
    const int ks = (s >> 6) & 3;
    const int l = s & 63;
    const int mm = tile * 64 + f * 16 + (l & 15);
    const bool mv = (mm < M_TOT);
    const int k0 = ks * 32 + (l >> 4) * 8;
    float v[8];
#pragma unroll
    for (int j = 0; j < 8; ++j) {
      const int k = k0 + j;
      float x = 0.f;
      if (k < CC) x = mv ? Cb[(size_t)k * M_TOT + mm] : 0.f;
      else if (k < 116) x = -0.125f * c2g[mm];
      v[j] = x;
    }
    uint4 pk;
    pk.x = (unsigned)f2bf(v[0]) | ((unsigned)f2bf(v[1]) << 16);
    pk.y = (unsigned)f2bf(v[2]) | ((unsigned)f2bf(v[3]) << 16);
    pk.z = (unsigned)f2bf(v[4]) | ((unsigned)f2bf(v[5]) << 16);
    pk.w = (unsigned)f2bf(v[6]) | ((unsigned)f2bf(v[7]) << 16);
    *(uint4*)(CT2 + (size_t)tile * 16384 + (size_t)s * 16) = pk;
  }
}

// ---- stage1: block = 128 rows x nT tiles of 64 m; 4 waves = 2 row-groups x 2 m-halves ----
__global__ __launch_bounds__(256, 2) void dsvdd_stage1(const float* __restrict__ phi,
                                                       const unsigned char* __restrict__ CT2,
                                                       float* __restrict__ part,
                                                       float* __restrict__ featg, int nT) {
  __shared__ __align__(16) unsigned char lds[49152];  // 3 x 16KB tile buffers

  const int t = threadIdx.x;
  const int lane = t & 63;
  const int w = t >> 6;
  const int g = w >> 1;  // row-group: rows [g*64, g*64+64)
  const int h = w & 1;   // m-half: fragments f = h*2, h*2+1
  const int cq = lane & 15;
  const int kq = lane >> 4;
  const int c = blockIdx.y;
  const int tile0 = c * nT;
  const long rowBase = (long)blockIdx.x * 128;

// stage one 16KB tile: each wave DMAs its 4KB quarter (LDS dest wave-uniform + lane*16)
#define STAGE(OFF, TIDX)                                                          \
  do {                                                                            \
    const unsigned char* _g =                                                     \
        CT2 + (size_t)(TIDX)*16384 + (size_t)w * 4096 + (size_t)lane * 16;        \
    unsigned char* _l = lds + (OFF) + w * 4096;                                   \
    _Pragma("unroll") for (int ii = 0; ii < 4; ++ii)                              \
        async16(_g + ii * 1024, _l + ii * 1024);                                  \
  } while (0)

  // ---- phi -> bg fragments (issued FIRST so stage loads are younger in vmcnt order) ----
  s16x8 bg[4][4];  // [ks][pf]
  float ssr[4];
#pragma unroll
  for (int pf = 0; pf < 4; ++pf) {
    ssr[pf] = 0.f;
    const float* rp = phi + (size_t)(rowBase + g * 64 + pf * 16 + cq) * CC;
#pragma unroll
    for (int ks = 0; ks < 4; ++ks) {
      const int k0 = ks * 32 + kq * 8;
      s16x8 v;
      if (k0 <= 104) {
        const float4 a = *(const float4*)(rp + k0);
        const float4 b = *(const float4*)(rp + k0 + 4);
        ssr[pf] += a.x * a.x + a.y * a.y + a.z * a.z + a.w * a.w;
        ssr[pf] += b.x * b.x + b.y * b.y + b.z * b.z + b.w * b.w;
        v[0] = (short)f2bf(a.x); v[1] = (short)f2bf(a.y);
        v[2] = (short)f2bf(a.z); v[3] = (short)f2bf(a.w);
        v[4] = (short)f2bf(b.x); v[5] = (short)f2bf(b.y);
        v[6] = (short)f2bf(b.z); v[7] = (short)f2bf(b.w);
      } else if (k0 == 112) {  // fold slots: four 1.0, four 0
        v[0] = v[1] = v[2] = v[3] = (short)0x3f80;
        v[4] = v[5] = v[6] = v[7] = 0;
      } else {
        v = (s16x8)0;
      }
      bg[ks][pf] = v;
    }
    ssr[pf] += __shfl_xor(ssr[pf], 16);
    ssr[pf] += __shfl_xor(ssr[pf], 32);
  }

  // prefetch tiles 0 and 1 (nT >= 10 always)
  STAGE(0, tile0 + 0);
  STAGE(16384, tile0 + 1);

  if (c == 0 && kq == 0) {
#pragma unroll
    for (int pf = 0; pf < 4; ++pf)
      featg[rowBase + g * 64 + pf * 16 + cq] = ssr[pf];
  }

  float t0[4], t1[4], t2[4];
#pragma unroll
  for (int pf = 0; pf < 4; ++pf) t0[pf] = t1[pf] = t2[pf] = -3.0e38f;

  // ---- main loop: one raw barrier + one counted vmcnt per tile; 2 tiles in flight ----
  int rd_off = 0;
  for (int tt = 0; tt < nT; ++tt) {
    if (tt + 1 < nT) {
      asm volatile("s_waitcnt vmcnt(4)" ::: "memory");  // this tile's 4 DMAs done
    } else {
      asm volatile("s_waitcnt vmcnt(0)" ::: "memory");  // last tile: drain
    }
    __builtin_amdgcn_s_barrier();  // all waves' quarters landed; prev buf free
    __builtin_amdgcn_sched_barrier(0);
    if (tt + 2 < nT) {
      int wr = rd_off + 32768;
      if (wr >= 49152) wr -= 49152;
      STAGE(wr, tile0 + tt + 2);
    }
    const unsigned char* rd = lds + rd_off;
#pragma unroll
    for (int mf = 0; mf < 2; ++mf) {
      const int f = h * 2 + mf;
      s16x8 af[4];
#pragma unroll
      for (int ks = 0; ks < 4; ++ks)
        af[ks] = *(const s16x8*)(rd + (f * 4 + ks) * 1024 + lane * 16);
      fx4 acc[4];
      const fx4 zz = {0.f, 0.f, 0.f, 0.f};
#pragma unroll
      for (int ks = 0; ks < 4; ++ks)
#pragma unroll
        for (int pf = 0; pf < 4; ++pf)
          acc[pf] = __builtin_amdgcn_mfma_f32_16x16x32_bf16(
              af[ks], bg[ks][pf], (ks == 0) ? zz : acc[pf], 0, 0, 0);
#pragma unroll
      for (int pf = 0; pf < 4; ++pf)
#pragma unroll
        for (int rg = 0; rg < 4; ++rg)
          INSERT3(t0[pf], t1[pf], t2[pf], acc[pf][rg]);
    }
    rd_off += 16384;
    if (rd_off == 49152) rd_off = 0;
  }
#undef STAGE

  // ---- merge the 4 kq groups within each wave ----
#pragma unroll
  for (int pf = 0; pf < 4; ++pf) {
#pragma unroll
    for (int off = 16; off < 64; off <<= 1) {
      const float b0 = __shfl_xor(t0[pf], off);
      const float b1 = __shfl_xor(t1[pf], off);
      const float b2 = __shfl_xor(t2[pf], off);
      INSERT3(t0[pf], t1[pf], t2[pf], b0);
      INSERT3(t0[pf], t1[pf], t2[pf], b1);
      INSERT3(t0[pf], t1[pf], t2[pf], b2);
    }
  }
  __syncthreads();  // everyone done with tile buffers; safe to alias merge scratch
  float(*const mg)[8] = (float(*)[8])lds;  // [128 rows][h*3 + 0..2]
  if (kq == 0) {
#pragma unroll
    for (int pf = 0; pf < 4; ++pf) {
      const int row = g * 64 + pf * 16 + cq;
      mg[row][h * 3 + 0] = t0[pf];
      mg[row][h * 3 + 1] = t1[pf];
      mg[row][h * 3 + 2] = t2[pf];
    }
  }
  __syncthreads();
  if (t < 128) {
    float s0 = mg[t][0], s1 = mg[t][1], s2 = mg[t][2];
    INSERT3(s0, s1, s2, mg[t][3]);
    INSERT3(s0, s1, s2, mg[t][4]);
    INSERT3(s0, s1, s2, mg[t][5]);
    float* dst = part + ((size_t)c * NROWS + rowBase + t) * 3;
    dst[0] = s0; dst[1] = s1; dst[2] = s2;
  }
}

// ---- stage2: merge S partial triples per row, sqrt + softmin, write score ----
__global__ __launch_bounds__(256) void dsvdd_stage2(const float* __restrict__ part,
                                                    const float* __restrict__ featg,
                                                    float* __restrict__ out, int S) {
  const int row = blockIdx.x * 256 + threadIdx.x;
  if (row >= NROWS) return;
  float s0 = -3.0e38f, s1 = -3.0e38f, s2 = -3.0e38f;
  for (int c = 0; c < S; ++c) {
    const float* p = part + ((size_t)c * NROWS + row) * 3;
    INSERT3(s0, s1, s2, p[0]);
    INSERT3(s0, s1, s2, p[1]);
    INSERT3(s0, s1, s2, p[2]);
  }
  const float feat = featg[row];
  const float d0 = sqrtf(fmaxf(feat - 2.f * s0, 0.f));
  const float d1 = sqrtf(fmaxf(feat - 2.f * s1, 0.f));
  const float d2 = sqrtf(fmaxf(feat - 2.f * s2, 0.f));
  const float w0 = 1.0f / (1.0f + __expf(d0 - d1) + __expf(d0 - d2));
  out[row] = w0 * d0;
}

extern "C" void kernel_launch(void* const* d_in, const int* in_sizes, int n_in,
                              void* d_out, int out_size, void* d_ws, size_t ws_size,
                              hipStream_t stream) {
  (void)in_sizes; (void)n_in; (void)out_size;
  const float* phi = (const float*)d_in[0];
  const float* Cb = (const float*)d_in[1];
  float* out = (float*)d_out;
  unsigned char* CT2 = (unsigned char*)d_ws;                     // 819200 B
  float* c2g = (float*)((unsigned char*)d_ws + 819200);          // 12800 B
  float* featg = (float*)((unsigned char*)d_ws + 832000);        // 200704 B
  float* partp = (float*)((unsigned char*)d_ws + 832000 + 200704);
  const size_t base = 832000 + 200704;
  int S = 1;
  if (ws_size >= base + (size_t)5 * NROWS * 12) S = 5;
  else if (ws_size >= base + (size_t)2 * NROWS * 12) S = 2;
  const int nT = N_TILES_TOT / S;
  dsvdd_prep0<<<13, 256, 0, stream>>>(Cb, c2g);
  dsvdd_prep1<<<50, 256, 0, stream>>>(Cb, c2g, CT2);
  dsvdd_stage1<<<dim3(392, S), 256, 0, stream>>>(phi, CT2, partp, featg, nT);
  dsvdd_stage2<<<196, 256, 0, stream>>>(partp, featg, out, S);
}

// Round 7
// 64.283 us; speedup vs baseline: 1.2345x; 1.1924x over previous
//
#include <hip/hip_runtime.h>
#include <stdint.h>

// DSVDD fused: dist = sqrt(||phi||^2 + ||c||^2 - 2 phi.c), top-3 smallest, softmin score.
// bf16 MFMA computes S = phi.c - ||c||^2/2 (centers folded into K-pad 112->128),
// track top-3 LARGEST S per row == 3 smallest distances.
// R7: BARRIER-FREE stage1. CT2 is fragment-ordered [tile][f][ks][lane]x16B, so a wave's
// af fragment load is a coalesced 1KB global read -> stream global->VGPR directly from
// L2 (no LDS staging, no per-tile barriers), double-buffered in named registers.
// LDS = 4KB epilogue scratch only -> occupancy VGPR-limited (~3 waves/SIMD).
// prep merged into one kernel (per-tile c2 in LDS). Two-stage top-3 as before (S=5).

typedef short s16x8 __attribute__((ext_vector_type(8)));
typedef float fx4 __attribute__((ext_vector_type(4)));

#define M_TOT 3136
#define CC 112
#define NROWS 50176
#define N_TILES_TOT 50  // 3200 m / 64 per tile; tile bytes = 64*256 = 16384

__device__ __forceinline__ unsigned short f2bf(float x) {
  unsigned u = __float_as_uint(x);
  u += 0x7fffu + ((u >> 16) & 1u);  // RNE
  return (unsigned short)(u >> 16);
}

// insert v into descending triple (t0 >= t1 >= t2), keep 3 largest. 3 VALU ops.
#define INSERT3(T0, T1, T2, V)                                  \
  do {                                                          \
    const float _a0 = (T0), _a1 = (T1), _v = (V);               \
    (T0) = fmaxf(_a0, _v);                                      \
    (T1) = __builtin_amdgcn_fmed3f(_a0, _a1, _v);               \
    (T2) = __builtin_amdgcn_fmed3f(_a1, (T2), _v);              \
  } while (0)

// ---- prep: CT2[tile][f][ks][lane] 16B slots, fragment-ordered for MFMA A-operand ----
// slot value: 8 bf16 = CT[m = tile*64+f*16+(lane&15)][k = ks*32+(lane>>4)*8 + 0..7]
// where CT[m][k] = C_bank[k][m] (k<112); -||c_m||^2/8 (112<=k<116, sentinel -2500); 0 else.
__global__ __launch_bounds__(256) void dsvdd_prep(const float* __restrict__ Cb,
                                                  unsigned char* __restrict__ CT2) {
  const int tile = blockIdx.x;
  __shared__ float partial[256];
  __shared__ float c2s[64];  // pre-scaled fold value per local m
  const int tm = threadIdx.x & 63;
  const int seg = threadIdx.x >> 6;
  const int m = tile * 64 + tm;
  float ss = 0.f;
  if (m < M_TOT) {
    for (int k = seg * 28; k < seg * 28 + 28; ++k) {
      const float x = Cb[(size_t)k * M_TOT + m];
      ss += x * x;
    }
  }
  partial[threadIdx.x] = ss;
  __syncthreads();
  if (seg == 0) {
    const float c2 = partial[tm] + partial[64 + tm] + partial[128 + tm] + partial[192 + tm];
    c2s[tm] = (m < M_TOT) ? (-0.125f * c2) : -2500.0f;  // sentinel: S ~ -1e4
  }
  __syncthreads();
#pragma unroll
  for (int it = 0; it < 4; ++it) {
    const int s = it * 256 + threadIdx.x;  // 0..1023 slots per tile
    const int f = s >> 8;
    const int ks = (s >> 6) & 3;
    const int l = s & 63;
    const int mloc = f * 16 + (l & 15);
    const int mm = tile * 64 + mloc;
    const bool mv = (mm < M_TOT);
    const int k0 = ks * 32 + (l >> 4) * 8;
    float v[8];
#pragma unroll
    for (int j = 0; j < 8; ++j) {
      const int k = k0 + j;
      float x = 0.f;
      if (k < CC) x = mv ? Cb[(size_t)k * M_TOT + mm] : 0.f;
      else if (k < 116) x = c2s[mloc];
      v[j] = x;
    }
    uint4 pk;
    pk.x = (unsigned)f2bf(v[0]) | ((unsigned)f2bf(v[1]) << 16);
    pk.y = (unsigned)f2bf(v[2]) | ((unsigned)f2bf(v[3]) << 16);
    pk.z = (unsigned)f2bf(v[4]) | ((unsigned)f2bf(v[5]) << 16);
    pk.w = (unsigned)f2bf(v[6]) | ((unsigned)f2bf(v[7]) << 16);
    *(uint4*)(CT2 + (size_t)tile * 16384 + (size_t)s * 16) = pk;
  }
}

// ---- stage1: block = 128 rows x nT tiles of 64 m; 4 waves = 2 row-groups x 2 m-halves.
// Barrier-free main loop: each wave streams its 2 fragments (8 coalesced 1KB loads/tile)
// global->reg from L2, double-buffered in named register sets afA/afB.
__global__ __launch_bounds__(256, 2) void dsvdd_stage1(const float* __restrict__ phi,
                                                       const unsigned char* __restrict__ CT2,
                                                       float* __restrict__ part,
                                                       float* __restrict__ featg, int nT) {
  __shared__ float mg[128][8];  // epilogue merge scratch (4.25KB)

  const int t = threadIdx.x;
  const int lane = t & 63;
  const int w = t >> 6;
  const int g = w >> 1;  // row-group: rows [g*64, g*64+64)
  const int h = w & 1;   // m-half: fragments f = h*2, h*2+1
  const int cq = lane & 15;
  const int kq = lane >> 4;
  const int c = blockIdx.y;
  const int tile0 = c * nT;
  const long rowBase = (long)blockIdx.x * 128;
  const bool needF = (c == 0);

  // ---- phi -> bg fragments directly (64 rows/wave, 64 VGPR) + row features (c==0) ----
  s16x8 bg[4][4];  // [ks][pf]
  float ssr[4];
#pragma unroll
  for (int pf = 0; pf < 4; ++pf) {
    ssr[pf] = 0.f;
    const float* rp = phi + (size_t)(rowBase + g * 64 + pf * 16 + cq) * CC;
#pragma unroll
    for (int ks = 0; ks < 4; ++ks) {
      const int k0 = ks * 32 + kq * 8;
      s16x8 v;
      if (k0 <= 104) {
        const float4 a = *(const float4*)(rp + k0);
        const float4 b = *(const float4*)(rp + k0 + 4);
        if (needF) {
          ssr[pf] += a.x * a.x + a.y * a.y + a.z * a.z + a.w * a.w;
          ssr[pf] += b.x * b.x + b.y * b.y + b.z * b.z + b.w * b.w;
        }
        v[0] = (short)f2bf(a.x); v[1] = (short)f2bf(a.y);
        v[2] = (short)f2bf(a.z); v[3] = (short)f2bf(a.w);
        v[4] = (short)f2bf(b.x); v[5] = (short)f2bf(b.y);
        v[6] = (short)f2bf(b.z); v[7] = (short)f2bf(b.w);
      } else if (k0 == 112) {  // fold slots: four 1.0, four 0
        v[0] = v[1] = v[2] = v[3] = (short)0x3f80;
        v[4] = v[5] = v[6] = v[7] = 0;
      } else {
        v = (s16x8)0;
      }
      bg[ks][pf] = v;
    }
    if (needF) {
      ssr[pf] += __shfl_xor(ssr[pf], 16);
      ssr[pf] += __shfl_xor(ssr[pf], 32);
    }
  }
  if (needF && kq == 0) {
#pragma unroll
    for (int pf = 0; pf < 4; ++pf)
      featg[rowBase + g * 64 + pf * 16 + cq] = ssr[pf];
  }

  float t0[4], t1[4], t2[4];
#pragma unroll
  for (int pf = 0; pf < 4; ++pf) t0[pf] = t1[pf] = t2[pf] = -3.0e38f;

  // ---- barrier-free main loop ----
  // af fragment load: CT2 + tile*16384 + (f*4+ks)*1024 + lane*16, f = h*2+mf
  const unsigned char* ap = CT2 + (size_t)(h * 2) * 4096 + (size_t)lane * 16;
  s16x8 afA[8], afB[8];  // named double buffers (compile-time indexed -> registers)

#define LOADAF(DST, TIDX)                                                     \
  do {                                                                        \
    const unsigned char* _p = ap + (size_t)(TIDX)*16384;                      \
    _Pragma("unroll") for (int mf = 0; mf < 2; ++mf)                          \
        _Pragma("unroll") for (int ks = 0; ks < 4; ++ks)                      \
            DST[mf * 4 + ks] = *(const s16x8*)(_p + mf * 4096 + ks * 1024);   \
  } while (0)

#define COMPUTE(SRC)                                                          \
  do {                                                                        \
    const fx4 _zz = {0.f, 0.f, 0.f, 0.f};                                     \
    _Pragma("unroll") for (int mf = 0; mf < 2; ++mf) {                        \
      fx4 acc[4];                                                             \
      _Pragma("unroll") for (int ks = 0; ks < 4; ++ks)                        \
          _Pragma("unroll") for (int pf = 0; pf < 4; ++pf)                    \
              acc[pf] = __builtin_amdgcn_mfma_f32_16x16x32_bf16(              \
                  SRC[mf * 4 + ks], bg[ks][pf], (ks == 0) ? _zz : acc[pf],    \
                  0, 0, 0);                                                   \
      _Pragma("unroll") for (int pf = 0; pf < 4; ++pf)                        \
          _Pragma("unroll") for (int rg = 0; rg < 4; ++rg)                    \
              INSERT3(t0[pf], t1[pf], t2[pf], acc[pf][rg]);                   \
    }                                                                         \
  } while (0)

  LOADAF(afA, tile0);
  int tt = 0;
  while (tt + 2 < nT) {
    LOADAF(afB, tile0 + tt + 1);
    COMPUTE(afA);
    LOADAF(afA, tile0 + tt + 2);
    COMPUTE(afB);
    tt += 2;
  }
  if (tt + 1 < nT) {  // even nT: one pair left
    LOADAF(afB, tile0 + tt + 1);
    COMPUTE(afA);
    COMPUTE(afB);
  } else {  // odd nT: single tile left
    COMPUTE(afA);
  }
#undef LOADAF
#undef COMPUTE

  // ---- merge the 4 kq groups within each wave ----
#pragma unroll
  for (int pf = 0; pf < 4; ++pf) {
#pragma unroll
    for (int off = 16; off < 64; off <<= 1) {
      const float b0 = __shfl_xor(t0[pf], off);
      const float b1 = __shfl_xor(t1[pf], off);
      const float b2 = __shfl_xor(t2[pf], off);
      INSERT3(t0[pf], t1[pf], t2[pf], b0);
      INSERT3(t0[pf], t1[pf], t2[pf], b1);
      INSERT3(t0[pf], t1[pf], t2[pf], b2);
    }
  }
  if (kq == 0) {
#pragma unroll
    for (int pf = 0; pf < 4; ++pf) {
      const int row = g * 64 + pf * 16 + cq;
      mg[row][h * 3 + 0] = t0[pf];
      mg[row][h * 3 + 1] = t1[pf];
      mg[row][h * 3 + 2] = t2[pf];
    }
  }
  __syncthreads();
  if (t < 128) {
    float s0 = mg[t][0], s1 = mg[t][1], s2 = mg[t][2];
    INSERT3(s0, s1, s2, mg[t][3]);
    INSERT3(s0, s1, s2, mg[t][4]);
    INSERT3(s0, s1, s2, mg[t][5]);
    float* dst = part + ((size_t)c * NROWS + rowBase + t) * 3;
    dst[0] = s0; dst[1] = s1; dst[2] = s2;
  }
}

// ---- stage2: merge S partial triples per row, sqrt + softmin, write score ----
__global__ __launch_bounds__(256) void dsvdd_stage2(const float* __restrict__ part,
                                                    const float* __restrict__ featg,
                                                    float* __restrict__ out, int S) {
  const int row = blockIdx.x * 256 + threadIdx.x;
  if (row >= NROWS) return;
  float s0 = -3.0e38f, s1 = -3.0e38f, s2 = -3.0e38f;
  for (int c = 0; c < S; ++c) {
    const float* p = part + ((size_t)c * NROWS + row) * 3;
    INSERT3(s0, s1, s2, p[0]);
    INSERT3(s0, s1, s2, p[1]);
    INSERT3(s0, s1, s2, p[2]);
  }
  const float feat = featg[row];
  const float d0 = sqrtf(fmaxf(feat - 2.f * s0, 0.f));
  const float d1 = sqrtf(fmaxf(feat - 2.f * s1, 0.f));
  const float d2 = sqrtf(fmaxf(feat - 2.f * s2, 0.f));
  const float w0 = 1.0f / (1.0f + __expf(d0 - d1) + __expf(d0 - d2));
  out[row] = w0 * d0;
}

extern "C" void kernel_launch(void* const* d_in, const int* in_sizes, int n_in,
                              void* d_out, int out_size, void* d_ws, size_t ws_size,
                              hipStream_t stream) {
  (void)in_sizes; (void)n_in; (void)out_size;
  const float* phi = (const float*)d_in[0];
  const float* Cb = (const float*)d_in[1];
  float* out = (float*)d_out;
  unsigned char* CT2 = (unsigned char*)d_ws;               // 819200 B
  float* featg = (float*)((unsigned char*)d_ws + 819200);  // 200704 B
  float* partp = (float*)((unsigned char*)d_ws + 819200 + 200704);
  const size_t base = 819200 + 200704;
  int S = 1;
  if (ws_size >= base + (size_t)5 * NROWS * 12) S = 5;
  else if (ws_size >= base + (size_t)2 * NROWS * 12) S = 2;
  const int nT = N_TILES_TOT / S;
  dsvdd_prep<<<50, 256, 0, stream>>>(Cb, CT2);
  dsvdd_stage1<<<dim3(392, S), 256, 0, stream>>>(phi, CT2, partp, featg, nT);
  dsvdd_stage2<<<196, 256, 0, stream>>>(partp, featg, out, S);
}

// Round 8
// 63.450 us; speedup vs baseline: 1.2507x; 1.0131x over previous
//
#include <hip/hip_runtime.h>
#include <stdint.h>

// DSVDD fused: dist = sqrt(||phi||^2 + ||c||^2 - 2 phi.c), top-3 smallest, softmin score.
// bf16 MFMA computes S = phi.c - ||c||^2/2 (centers folded into K-pad 112->128),
// track top-3 LARGEST S per row == 3 smallest distances.
// R8: R7 structure (barrier-free af streaming from fragment-ordered CT2, two-stage top-3)
// plus: (a) launch_bounds(256,3) -> 3 blocks/CU (R7 was latency-bound at 2 waves/EU);
// (b) coalesced phi prologue: contiguous row reads -> fragment-ordered LDS -> ds_read_b128
// (R7's direct per-lane phi loads touched ~64 cache lines per instruction).

typedef short s16x8 __attribute__((ext_vector_type(8)));
typedef float fx4 __attribute__((ext_vector_type(4)));

#define M_TOT 3136
#define CC 112
#define NROWS 50176
#define N_TILES_TOT 50  // 3200 m / 64 per tile; tile bytes = 64*256 = 16384

__device__ __forceinline__ unsigned short f2bf(float x) {
  unsigned u = __float_as_uint(x);
  u += 0x7fffu + ((u >> 16) & 1u);  // RNE
  return (unsigned short)(u >> 16);
}

// insert v into descending triple (t0 >= t1 >= t2), keep 3 largest. 3 VALU ops.
#define INSERT3(T0, T1, T2, V)                                  \
  do {                                                          \
    const float _a0 = (T0), _a1 = (T1), _v = (V);               \
    (T0) = fmaxf(_a0, _v);                                      \
    (T1) = __builtin_amdgcn_fmed3f(_a0, _a1, _v);               \
    (T2) = __builtin_amdgcn_fmed3f(_a1, (T2), _v);              \
  } while (0)

// ---- prep: CT2[tile][f][ks][lane] 16B slots, fragment-ordered for MFMA A-operand ----
// slot value: 8 bf16 = CT[m = tile*64+f*16+(lane&15)][k = ks*32+(lane>>4)*8 + 0..7]
// where CT[m][k] = C_bank[k][m] (k<112); -||c_m||^2/8 (112<=k<116, sentinel -2500); 0 else.
__global__ __launch_bounds__(256) void dsvdd_prep(const float* __restrict__ Cb,
                                                  unsigned char* __restrict__ CT2) {
  const int tile = blockIdx.x;
  __shared__ float partial[256];
  __shared__ float c2s[64];  // pre-scaled fold value per local m
  const int tm = threadIdx.x & 63;
  const int seg = threadIdx.x >> 6;
  const int m = tile * 64 + tm;
  float ss = 0.f;
  if (m < M_TOT) {
    for (int k = seg * 28; k < seg * 28 + 28; ++k) {
      const float x = Cb[(size_t)k * M_TOT + m];
      ss += x * x;
    }
  }
  partial[threadIdx.x] = ss;
  __syncthreads();
  if (seg == 0) {
    const float c2 = partial[tm] + partial[64 + tm] + partial[128 + tm] + partial[192 + tm];
    c2s[tm] = (m < M_TOT) ? (-0.125f * c2) : -2500.0f;  // sentinel: S ~ -1e4
  }
  __syncthreads();
#pragma unroll
  for (int it = 0; it < 4; ++it) {
    const int s = it * 256 + threadIdx.x;  // 0..1023 slots per tile
    const int f = s >> 8;
    const int ks = (s >> 6) & 3;
    const int l = s & 63;
    const int mloc = f * 16 + (l & 15);
    const int mm = tile * 64 + mloc;
    const bool mv = (mm < M_TOT);
    const int k0 = ks * 32 + (l >> 4) * 8;
    float v[8];
#pragma unroll
    for (int j = 0; j < 8; ++j) {
      const int k = k0 + j;
      float x = 0.f;
      if (k < CC) x = mv ? Cb[(size_t)k * M_TOT + mm] : 0.f;
      else if (k < 116) x = c2s[mloc];
      v[j] = x;
    }
    uint4 pk;
    pk.x = (unsigned)f2bf(v[0]) | ((unsigned)f2bf(v[1]) << 16);
    pk.y = (unsigned)f2bf(v[2]) | ((unsigned)f2bf(v[3]) << 16);
    pk.z = (unsigned)f2bf(v[4]) | ((unsigned)f2bf(v[5]) << 16);
    pk.w = (unsigned)f2bf(v[6]) | ((unsigned)f2bf(v[7]) << 16);
    *(uint4*)(CT2 + (size_t)tile * 16384 + (size_t)s * 16) = pk;
  }
}

// ---- stage1: block = 128 rows x nT tiles of 64 m; 4 waves = 2 row-groups x 2 m-halves.
// Barrier-free main loop: each wave streams its 2 fragments (8 coalesced 1KB loads/tile)
// global->reg from L2, double-buffered in named register sets afA/afB.
__global__ __launch_bounds__(256, 3) void dsvdd_stage1(const float* __restrict__ phi,
                                                       const unsigned char* __restrict__ CT2,
                                                       float* __restrict__ part,
                                                       float* __restrict__ featg, int nT) {
  // phi fragments staged in fragment order [g][pf][ks][lane]x16B = 32KB;
  // aliased by the 4KB epilogue merge scratch after extraction.
  __shared__ __align__(16) unsigned char phiF[32768];
  float(*const mg)[8] = (float(*)[8])phiF;

  const int t = threadIdx.x;
  const int lane = t & 63;
  const int w = t >> 6;
  const int g = w >> 1;  // row-group: rows [g*64, g*64+64)
  const int h = w & 1;   // m-half: fragments f = h*2, h*2+1
  const int cq = lane & 15;
  const int kq = lane >> 4;
  const int c = blockIdx.y;
  const int tile0 = c * nT;
  const long rowBase = (long)blockIdx.x * 128;
  const bool needF = (c == 0);

  // ---- coalesced phi prologue: 2 threads/row read 448B runs, write bf16 slots ----
  {
    const int r = t >> 1;
    const int h2 = t & 1;
    const float* src = phi + (size_t)(rowBase + r) * CC + h2 * 56;
    unsigned char* const base = phiF + (((r >> 4) * 4) * 1024);  // (g*4+pf) = r>>4
    const int pcq = r & 15;
    float ss = 0.f;
#pragma unroll
    for (int j = 0; j < 7; ++j) {
      const int k0 = h2 * 56 + j * 8;
      const int ks = k0 >> 5;
      const int kqw = (k0 >> 3) & 3;
      const float4 a = *(const float4*)(src + j * 8);
      const float4 b = *(const float4*)(src + j * 8 + 4);
      ss += a.x * a.x + a.y * a.y + a.z * a.z + a.w * a.w;
      ss += b.x * b.x + b.y * b.y + b.z * b.z + b.w * b.w;
      uint4 pk;
      pk.x = (unsigned)f2bf(a.x) | ((unsigned)f2bf(a.y) << 16);
      pk.y = (unsigned)f2bf(a.z) | ((unsigned)f2bf(a.w) << 16);
      pk.z = (unsigned)f2bf(b.x) | ((unsigned)f2bf(b.y) << 16);
      pk.w = (unsigned)f2bf(b.z) | ((unsigned)f2bf(b.w) << 16);
      *(uint4*)(base + ks * 1024 + (kqw * 16 + pcq) * 16) = pk;
    }
    {  // K-pad: h2==0 -> fold slot (ks=3,kq=2) = {1,1,1,1,0,0,0,0}; h2==1 -> (3,3)=0
      uint4 pk;
      if (h2 == 0) { pk.x = 0x3f803f80u; pk.y = 0x3f803f80u; pk.z = 0u; pk.w = 0u; }
      else { pk.x = pk.y = pk.z = pk.w = 0u; }
      *(uint4*)(base + 3 * 1024 + ((2 + h2) * 16 + pcq) * 16) = pk;
    }
    ss += __shfl_xor(ss, 1);
    if (needF && h2 == 0) featg[rowBase + r] = ss;
  }
  __syncthreads();

  // ---- extract bg fragments: contiguous conflict-free ds_read_b128 ----
  s16x8 bg[4][4];  // [ks][pf]
#pragma unroll
  for (int ks = 0; ks < 4; ++ks)
#pragma unroll
    for (int pf = 0; pf < 4; ++pf)
      bg[ks][pf] = *(const s16x8*)(phiF + (((g * 4 + pf) * 4 + ks) * 64 + lane) * 16);
  __syncthreads();  // all reads done before mg alias is written in the epilogue

  float t0[4], t1[4], t2[4];
#pragma unroll
  for (int pf = 0; pf < 4; ++pf) t0[pf] = t1[pf] = t2[pf] = -3.0e38f;

  // ---- barrier-free main loop ----
  // af fragment load: CT2 + tile*16384 + (f*4+ks)*1024 + lane*16, f = h*2+mf
  const unsigned char* ap = CT2 + (size_t)(h * 2) * 4096 + (size_t)lane * 16;
  s16x8 afA[8], afB[8];  // named double buffers (compile-time indexed -> registers)

#define LOADAF(DST, TIDX)                                                     \
  do {                                                                        \
    const unsigned char* _p = ap + (size_t)(TIDX)*16384;                      \
    _Pragma("unroll") for (int mf = 0; mf < 2; ++mf)                          \
        _Pragma("unroll") for (int ks = 0; ks < 4; ++ks)                      \
            DST[mf * 4 + ks] = *(const s16x8*)(_p + mf * 4096 + ks * 1024);   \
  } while (0)

#define COMPUTE(SRC)                                                          \
  do {                                                                        \
    const fx4 _zz = {0.f, 0.f, 0.f, 0.f};                                     \
    _Pragma("unroll") for (int mf = 0; mf < 2; ++mf) {                        \
      fx4 acc[4];                                                             \
      _Pragma("unroll") for (int ks = 0; ks < 4; ++ks)                        \
          _Pragma("unroll") for (int pf = 0; pf < 4; ++pf)                    \
              acc[pf] = __builtin_amdgcn_mfma_f32_16x16x32_bf16(              \
                  SRC[mf * 4 + ks], bg[ks][pf], (ks == 0) ? _zz : acc[pf],    \
                  0, 0, 0);                                                   \
      _Pragma("unroll") for (int pf = 0; pf < 4; ++pf)                        \
          _Pragma("unroll") for (int rg = 0; rg < 4; ++rg)                    \
              INSERT3(t0[pf], t1[pf], t2[pf], acc[pf][rg]);                   \
    }                                                                         \
  } while (0)

  LOADAF(afA, tile0);
  int tt = 0;
  while (tt + 2 < nT) {
    LOADAF(afB, tile0 + tt + 1);
    COMPUTE(afA);
    LOADAF(afA, tile0 + tt + 2);
    COMPUTE(afB);
    tt += 2;
  }
  if (tt + 1 < nT) {  // even nT: one pair left
    LOADAF(afB, tile0 + tt + 1);
    COMPUTE(afA);
    COMPUTE(afB);
  } else {  // odd nT: single tile left
    COMPUTE(afA);
  }
#undef LOADAF
#undef COMPUTE

  // ---- merge the 4 kq groups within each wave ----
#pragma unroll
  for (int pf = 0; pf < 4; ++pf) {
#pragma unroll
    for (int off = 16; off < 64; off <<= 1) {
      const float b0 = __shfl_xor(t0[pf], off);
      const float b1 = __shfl_xor(t1[pf], off);
      const float b2 = __shfl_xor(t2[pf], off);
      INSERT3(t0[pf], t1[pf], t2[pf], b0);
      INSERT3(t0[pf], t1[pf], t2[pf], b1);
      INSERT3(t0[pf], t1[pf], t2[pf], b2);
    }
  }
  if (kq == 0) {
#pragma unroll
    for (int pf = 0; pf < 4; ++pf) {
      const int row = g * 64 + pf * 16 + cq;
      mg[row][h * 3 + 0] = t0[pf];
      mg[row][h * 3 + 1] = t1[pf];
      mg[row][h * 3 + 2] = t2[pf];
    }
  }
  __syncthreads();
  if (t < 128) {
    float s0 = mg[t][0], s1 = mg[t][1], s2 = mg[t][2];
    INSERT3(s0, s1, s2, mg[t][3]);
    INSERT3(s0, s1, s2, mg[t][4]);
    INSERT3(s0, s1, s2, mg[t][5]);
    float* dst = part + ((size_t)c * NROWS + rowBase + t) * 3;
    dst[0] = s0; dst[1] = s1; dst[2] = s2;
  }
}

// ---- stage2: merge S partial triples per row, sqrt + softmin, write score ----
__global__ __launch_bounds__(256) void dsvdd_stage2(const float* __restrict__ part,
                                                    const float* __restrict__ featg,
                                                    float* __restrict__ out, int S) {
  const int row = blockIdx.x * 256 + threadIdx.x;
  if (row >= NROWS) return;
  float s0 = -3.0e38f, s1 = -3.0e38f, s2 = -3.0e38f;
  for (int c = 0; c < S; ++c) {
    const float* p = part + ((size_t)c * NROWS + row) * 3;
    INSERT3(s0, s1, s2, p[0]);
    INSERT3(s0, s1, s2, p[1]);
    INSERT3(s0, s1, s2, p[2]);
  }
  const float feat = featg[row];
  const float d0 = sqrtf(fmaxf(feat - 2.f * s0, 0.f));
  const float d1 = sqrtf(fmaxf(feat - 2.f * s1, 0.f));
  const float d2 = sqrtf(fmaxf(feat - 2.f * s2, 0.f));
  const float w0 = 1.0f / (1.0f + __expf(d0 - d1) + __expf(d0 - d2));
  out[row] = w0 * d0;
}

extern "C" void kernel_launch(void* const* d_in, const int* in_sizes, int n_in,
                              void* d_out, int out_size, void* d_ws, size_t ws_size,
                              hipStream_t stream) {
  (void)in_sizes; (void)n_in; (void)out_size;
  const float* phi = (const float*)d_in[0];
  const float* Cb = (const float*)d_in[1];
  float* out = (float*)d_out;
  unsigned char* CT2 = (unsigned char*)d_ws;               // 819200 B
  float* featg = (float*)((unsigned char*)d_ws + 819200);  // 200704 B
  float* partp = (float*)((unsigned char*)d_ws + 819200 + 200704);
  const size_t base = 819200 + 200704;
  int S = 1;
  if (ws_size >= base + (size_t)5 * NROWS * 12) S = 5;
  else if (ws_size >= base + (size_t)2 * NROWS * 12) S = 2;
  const int nT = N_TILES_TOT / S;
  dsvdd_prep<<<50, 256, 0, stream>>>(Cb, CT2);
  dsvdd_stage1<<<dim3(392, S), 256, 0, stream>>>(phi, CT2, partp, featg, nT);
  dsvdd_stage2<<<196, 256, 0, stream>>>(partp, featg, out, S);
}

// Round 9
// 63.380 us; speedup vs baseline: 1.2521x; 1.0011x over previous
//
#include <hip/hip_runtime.h>
#include <stdint.h>

// DSVDD fused: dist = sqrt(||phi||^2 + ||c||^2 - 2 phi.c), top-3 smallest, softmin score.
// bf16 MFMA computes S = phi.c - ||c||^2/2 (centers folded into K-pad 112->128),
// track top-3 LARGEST S per row == 3 smallest distances.
// R9: R8 + TILE STAGGER. All blocks of a chunk previously walked the same tile
// sequence in lockstep -> 392 blocks hammering the same 16KB of CT2 in L2 at once
// (same-line bank contention; per-block wall 15us vs ~2us pipe-busy). Each block now
// starts at tile (blockIdx.x % nT) and wraps, spreading readers across the chunk.

typedef short s16x8 __attribute__((ext_vector_type(8)));
typedef float fx4 __attribute__((ext_vector_type(4)));

#define M_TOT 3136
#define CC 112
#define NROWS 50176
#define N_TILES_TOT 50  // 3200 m / 64 per tile; tile bytes = 64*256 = 16384

__device__ __forceinline__ unsigned short f2bf(float x) {
  unsigned u = __float_as_uint(x);
  u += 0x7fffu + ((u >> 16) & 1u);  // RNE
  return (unsigned short)(u >> 16);
}

// insert v into descending triple (t0 >= t1 >= t2), keep 3 largest. 3 VALU ops.
#define INSERT3(T0, T1, T2, V)                                  \
  do {                                                          \
    const float _a0 = (T0), _a1 = (T1), _v = (V);               \
    (T0) = fmaxf(_a0, _v);                                      \
    (T1) = __builtin_amdgcn_fmed3f(_a0, _a1, _v);               \
    (T2) = __builtin_amdgcn_fmed3f(_a1, (T2), _v);              \
  } while (0)

// ---- prep: CT2[tile][f][ks][lane] 16B slots, fragment-ordered for MFMA A-operand ----
// slot value: 8 bf16 = CT[m = tile*64+f*16+(lane&15)][k = ks*32+(lane>>4)*8 + 0..7]
// where CT[m][k] = C_bank[k][m] (k<112); -||c_m||^2/8 (112<=k<116, sentinel -2500); 0 else.
__global__ __launch_bounds__(256) void dsvdd_prep(const float* __restrict__ Cb,
                                                  unsigned char* __restrict__ CT2) {
  const int tile = blockIdx.x;
  __shared__ float partial[256];
  __shared__ float c2s[64];  // pre-scaled fold value per local m
  const int tm = threadIdx.x & 63;
  const int seg = threadIdx.x >> 6;
  const int m = tile * 64 + tm;
  float ss = 0.f;
  if (m < M_TOT) {
    for (int k = seg * 28; k < seg * 28 + 28; ++k) {
      const float x = Cb[(size_t)k * M_TOT + m];
      ss += x * x;
    }
  }
  partial[threadIdx.x] = ss;
  __syncthreads();
  if (seg == 0) {
    const float c2 = partial[tm] + partial[64 + tm] + partial[128 + tm] + partial[192 + tm];
    c2s[tm] = (m < M_TOT) ? (-0.125f * c2) : -2500.0f;  // sentinel: S ~ -1e4
  }
  __syncthreads();
#pragma unroll
  for (int it = 0; it < 4; ++it) {
    const int s = it * 256 + threadIdx.x;  // 0..1023 slots per tile
    const int f = s >> 8;
    const int ks = (s >> 6) & 3;
    const int l = s & 63;
    const int mloc = f * 16 + (l & 15);
    const int mm = tile * 64 + mloc;
    const bool mv = (mm < M_TOT);
    const int k0 = ks * 32 + (l >> 4) * 8;
    float v[8];
#pragma unroll
    for (int j = 0; j < 8; ++j) {
      const int k = k0 + j;
      float x = 0.f;
      if (k < CC) x = mv ? Cb[(size_t)k * M_TOT + mm] : 0.f;
      else if (k < 116) x = c2s[mloc];
      v[j] = x;
    }
    uint4 pk;
    pk.x = (unsigned)f2bf(v[0]) | ((unsigned)f2bf(v[1]) << 16);
    pk.y = (unsigned)f2bf(v[2]) | ((unsigned)f2bf(v[3]) << 16);
    pk.z = (unsigned)f2bf(v[4]) | ((unsigned)f2bf(v[5]) << 16);
    pk.w = (unsigned)f2bf(v[6]) | ((unsigned)f2bf(v[7]) << 16);
    *(uint4*)(CT2 + (size_t)tile * 16384 + (size_t)s * 16) = pk;
  }
}

// ---- stage1: block = 128 rows x nT tiles of 64 m; 4 waves = 2 row-groups x 2 m-halves.
// Barrier-free main loop: each wave streams its 2 fragments (8 coalesced 1KB loads/tile)
// global->reg from L2, double-buffered in named register sets afA/afB.
// Tile order rotated per block: j0 = blockIdx.x % nT.
__global__ __launch_bounds__(256, 3) void dsvdd_stage1(const float* __restrict__ phi,
                                                       const unsigned char* __restrict__ CT2,
                                                       float* __restrict__ part,
                                                       float* __restrict__ featg, int nT) {
  // phi fragments staged in fragment order [g][pf][ks][lane]x16B = 32KB;
  // aliased by the 4KB epilogue merge scratch after extraction.
  __shared__ __align__(16) unsigned char phiF[32768];
  float(*const mg)[8] = (float(*)[8])phiF;

  const int t = threadIdx.x;
  const int lane = t & 63;
  const int w = t >> 6;
  const int g = w >> 1;  // row-group: rows [g*64, g*64+64)
  const int h = w & 1;   // m-half: fragments f = h*2, h*2+1
  const int cq = lane & 15;
  const int kq = lane >> 4;
  const int c = blockIdx.y;
  const int tile0 = c * nT;
  const long rowBase = (long)blockIdx.x * 128;
  const bool needF = (c == 0);

  // ---- coalesced phi prologue: 2 threads/row read 448B runs, write bf16 slots ----
  {
    const int r = t >> 1;
    const int h2 = t & 1;
    const float* src = phi + (size_t)(rowBase + r) * CC + h2 * 56;
    unsigned char* const base = phiF + (((r >> 4) * 4) * 1024);  // (g*4+pf) = r>>4
    const int pcq = r & 15;
    float ss = 0.f;
#pragma unroll
    for (int j = 0; j < 7; ++j) {
      const int k0 = h2 * 56 + j * 8;
      const int ks = k0 >> 5;
      const int kqw = (k0 >> 3) & 3;
      const float4 a = *(const float4*)(src + j * 8);
      const float4 b = *(const float4*)(src + j * 8 + 4);
      ss += a.x * a.x + a.y * a.y + a.z * a.z + a.w * a.w;
      ss += b.x * b.x + b.y * b.y + b.z * b.z + b.w * b.w;
      uint4 pk;
      pk.x = (unsigned)f2bf(a.x) | ((unsigned)f2bf(a.y) << 16);
      pk.y = (unsigned)f2bf(a.z) | ((unsigned)f2bf(a.w) << 16);
      pk.z = (unsigned)f2bf(b.x) | ((unsigned)f2bf(b.y) << 16);
      pk.w = (unsigned)f2bf(b.z) | ((unsigned)f2bf(b.w) << 16);
      *(uint4*)(base + ks * 1024 + (kqw * 16 + pcq) * 16) = pk;
    }
    {  // K-pad: h2==0 -> fold slot (ks=3,kq=2) = {1,1,1,1,0,0,0,0}; h2==1 -> (3,3)=0
      uint4 pk;
      if (h2 == 0) { pk.x = 0x3f803f80u; pk.y = 0x3f803f80u; pk.z = 0u; pk.w = 0u; }
      else { pk.x = pk.y = pk.z = pk.w = 0u; }
      *(uint4*)(base + 3 * 1024 + ((2 + h2) * 16 + pcq) * 16) = pk;
    }
    ss += __shfl_xor(ss, 1);
    if (needF && h2 == 0) featg[rowBase + r] = ss;
  }
  __syncthreads();

  // ---- extract bg fragments: contiguous conflict-free ds_read_b128 ----
  s16x8 bg[4][4];  // [ks][pf]
#pragma unroll
  for (int ks = 0; ks < 4; ++ks)
#pragma unroll
    for (int pf = 0; pf < 4; ++pf)
      bg[ks][pf] = *(const s16x8*)(phiF + (((g * 4 + pf) * 4 + ks) * 64 + lane) * 16);
  __syncthreads();  // all reads done before mg alias is written in the epilogue

  float t0[4], t1[4], t2[4];
#pragma unroll
  for (int pf = 0; pf < 4; ++pf) t0[pf] = t1[pf] = t2[pf] = -3.0e38f;

  // ---- barrier-free main loop, tile order rotated by blockIdx.x % nT ----
  // af fragment load: CT2 + tile*16384 + (f*4+ks)*1024 + lane*16, f = h*2+mf
  const unsigned char* ap = CT2 + (size_t)(h * 2) * 4096 + (size_t)lane * 16;
  s16x8 afA[8], afB[8];  // named double buffers (compile-time indexed -> registers)

#define NXJ(J) ((J) + 1 < nT ? (J) + 1 : 0)
#define LOADAF(DST, TIDX)                                                     \
  do {                                                                        \
    const unsigned char* _p = ap + (size_t)(TIDX)*16384;                      \
    _Pragma("unroll") for (int mf = 0; mf < 2; ++mf)                          \
        _Pragma("unroll") for (int ks = 0; ks < 4; ++ks)                      \
            DST[mf * 4 + ks] = *(const s16x8*)(_p + mf * 4096 + ks * 1024);   \
  } while (0)

#define COMPUTE(SRC)                                                          \
  do {                                                                        \
    const fx4 _zz = {0.f, 0.f, 0.f, 0.f};                                     \
    _Pragma("unroll") for (int mf = 0; mf < 2; ++mf) {                        \
      fx4 acc[4];                                                             \
      _Pragma("unroll") for (int ks = 0; ks < 4; ++ks)                        \
          _Pragma("unroll") for (int pf = 0; pf < 4; ++pf)                    \
              acc[pf] = __builtin_amdgcn_mfma_f32_16x16x32_bf16(              \
                  SRC[mf * 4 + ks], bg[ks][pf], (ks == 0) ? _zz : acc[pf],    \
                  0, 0, 0);                                                   \
      _Pragma("unroll") for (int pf = 0; pf < 4; ++pf)                        \
          _Pragma("unroll") for (int rg = 0; rg < 4; ++rg)                    \
              INSERT3(t0[pf], t1[pf], t2[pf], acc[pf][rg]);                   \
    }                                                                         \
  } while (0)

  int j = (int)blockIdx.x % nT;  // staggered start tile within this chunk
  LOADAF(afA, tile0 + j); j = NXJ(j);
  int tt = 0;
  while (tt + 2 < nT) {
    LOADAF(afB, tile0 + j); j = NXJ(j);
    COMPUTE(afA);
    LOADAF(afA, tile0 + j); j = NXJ(j);
    COMPUTE(afB);
    tt += 2;
  }
  if (tt + 1 < nT) {  // even nT: one pair left
    LOADAF(afB, tile0 + j);
    COMPUTE(afA);
    COMPUTE(afB);
  } else {  // odd nT: single tile left
    COMPUTE(afA);
  }
#undef LOADAF
#undef COMPUTE
#undef NXJ

  // ---- merge the 4 kq groups within each wave ----
#pragma unroll
  for (int pf = 0; pf < 4; ++pf) {
#pragma unroll
    for (int off = 16; off < 64; off <<= 1) {
      const float b0 = __shfl_xor(t0[pf], off);
      const float b1 = __shfl_xor(t1[pf], off);
      const float b2 = __shfl_xor(t2[pf], off);
      INSERT3(t0[pf], t1[pf], t2[pf], b0);
      INSERT3(t0[pf], t1[pf], t2[pf], b1);
      INSERT3(t0[pf], t1[pf], t2[pf], b2);
    }
  }
  if (kq == 0) {
#pragma unroll
    for (int pf = 0; pf < 4; ++pf) {
      const int row = g * 64 + pf * 16 + cq;
      mg[row][h * 3 + 0] = t0[pf];
      mg[row][h * 3 + 1] = t1[pf];
      mg[row][h * 3 + 2] = t2[pf];
    }
  }
  __syncthreads();
  if (t < 128) {
    float s0 = mg[t][0], s1 = mg[t][1], s2 = mg[t][2];
    INSERT3(s0, s1, s2, mg[t][3]);
    INSERT3(s0, s1, s2, mg[t][4]);
    INSERT3(s0, s1, s2, mg[t][5]);
    float* dst = part + ((size_t)c * NROWS + rowBase + t) * 3;
    dst[0] = s0; dst[1] = s1; dst[2] = s2;
  }
}

// ---- stage2: merge S partial triples per row, sqrt + softmin, write score ----
__global__ __launch_bounds__(256) void dsvdd_stage2(const float* __restrict__ part,
                                                    const float* __restrict__ featg,
                                                    float* __restrict__ out, int S) {
  const int row = blockIdx.x * 256 + threadIdx.x;
  if (row >= NROWS) return;
  float s0 = -3.0e38f, s1 = -3.0e38f, s2 = -3.0e38f;
  for (int c = 0; c < S; ++c) {
    const float* p = part + ((size_t)c * NROWS + row) * 3;
    INSERT3(s0, s1, s2, p[0]);
    INSERT3(s0, s1, s2, p[1]);
    INSERT3(s0, s1, s2, p[2]);
  }
  const float feat = featg[row];
  const float d0 = sqrtf(fmaxf(feat - 2.f * s0, 0.f));
  const float d1 = sqrtf(fmaxf(feat - 2.f * s1, 0.f));
  const float d2 = sqrtf(fmaxf(feat - 2.f * s2, 0.f));
  const float w0 = 1.0f / (1.0f + __expf(d0 - d1) + __expf(d0 - d2));
  out[row] = w0 * d0;
}

extern "C" void kernel_launch(void* const* d_in, const int* in_sizes, int n_in,
                              void* d_out, int out_size, void* d_ws, size_t ws_size,
                              hipStream_t stream) {
  (void)in_sizes; (void)n_in; (void)out_size;
  const float* phi = (const float*)d_in[0];
  const float* Cb = (const float*)d_in[1];
  float* out = (float*)d_out;
  unsigned char* CT2 = (unsigned char*)d_ws;               // 819200 B
  float* featg = (float*)((unsigned char*)d_ws + 819200);  // 200704 B
  float* partp = (float*)((unsigned char*)d_ws + 819200 + 200704);
  const size_t base = 819200 + 200704;
  int S = 1;
  if (ws_size >= base + (size_t)5 * NROWS * 12) S = 5;
  else if (ws_size >= base + (size_t)2 * NROWS * 12) S = 2;
  const int nT = N_TILES_TOT / S;
  dsvdd_prep<<<50, 256, 0, stream>>>(Cb, CT2);
  dsvdd_stage1<<<dim3(392, S), 256, 0, stream>>>(phi, CT2, partp, featg, nT);
  dsvdd_stage2<<<196, 256, 0, stream>>>(partp, featg, out, S);
}